// Round 1
// baseline (220.913 us; speedup 1.0000x reference)
//
#include <hip/hip_runtime.h>

// Problem constants (from reference): B=8, H=16, T=16, D=128, S=4096
constexpr int B = 8;
constexpr int H = 16;
constexpr int T = 16;
constexpr int D = 128;
constexpr int S = 4096;
constexpr int D4 = D / 4;                       // float4 per row = 32
constexpr size_t CACHE_ELEMS = (size_t)B * H * S * D;   // 67,108,864 floats
constexpr size_t CACHE_F4    = CACHE_ELEMS / 4;         // 16,777,216 float4
constexpr int NEW_F4 = B * H * T * D4;                  // 65,536 float4 per tensor

// Kernel 1: copy both caches to the two output halves, vectorized float4.
__global__ void kv_copy_kernel(const float4* __restrict__ k_cache,
                               const float4* __restrict__ v_cache,
                               float4* __restrict__ out_k,
                               float4* __restrict__ out_v) {
    size_t i = (size_t)blockIdx.x * blockDim.x + threadIdx.x;
    size_t stride = (size_t)gridDim.x * blockDim.x;
    for (; i < CACHE_F4; i += stride) {
        out_k[i] = k_cache[i];
        out_v[i] = v_cache[i];
    }
}

// Kernel 2: scatter new k/v rows into the outputs at input_pos along S.
// k,v layout: (B, H, T, D). out layout: (B, H, S, D).
__global__ void kv_scatter_kernel(const int* __restrict__ input_pos,  // (B, T)
                                  const float4* __restrict__ k_new,
                                  const float4* __restrict__ v_new,
                                  float4* __restrict__ out_k,
                                  float4* __restrict__ out_v) {
    int i = blockIdx.x * blockDim.x + threadIdx.x;
    if (i >= NEW_F4) return;
    int d  = i % D4;
    int t  = (i / D4) % T;
    int h  = (i / (D4 * T)) % H;
    int b  = i / (D4 * T * H);
    int p  = input_pos[b * T + t];               // 0 <= p < S
    size_t dst = (((size_t)b * H + h) * S + p) * D4 + d;
    out_k[dst] = k_new[i];
    out_v[dst] = v_new[i];
}

extern "C" void kernel_launch(void* const* d_in, const int* in_sizes, int n_in,
                              void* d_out, int out_size, void* d_ws, size_t ws_size,
                              hipStream_t stream) {
    // setup_inputs order: input_pos, k, v, k_cache, v_cache
    const int*    input_pos = (const int*)d_in[0];
    const float4* k_new     = (const float4*)d_in[1];
    const float4* v_new     = (const float4*)d_in[2];
    const float4* k_cache   = (const float4*)d_in[3];
    const float4* v_cache   = (const float4*)d_in[4];

    float* out = (float*)d_out;
    float4* out_k = (float4*)out;
    float4* out_v = (float4*)(out + CACHE_ELEMS);

    // Copy: 2048 blocks x 256 threads, grid-stride (~32 iters/lane).
    kv_copy_kernel<<<2048, 256, 0, stream>>>(k_cache, v_cache, out_k, out_v);

    // Scatter: 65,536 float4 lanes -> 256 blocks x 256 threads.
    kv_scatter_kernel<<<(NEW_F4 + 255) / 256, 256, 0, stream>>>(
        input_pos, k_new, v_new, out_k, out_v);
}

// Round 2
// 207.834 us; speedup vs baseline: 1.0629x; 1.0629x over previous
//
#include <hip/hip_runtime.h>

// Problem constants (from reference): B=8, H=16, T=16, D=128, S=4096
constexpr int B = 8;
constexpr int H = 16;
constexpr int T = 16;
constexpr int D = 128;
constexpr int S = 4096;
constexpr int D4 = D / 4;                              // float4 per row = 32
constexpr size_t CACHE_ELEMS = (size_t)B * H * S * D;  // 67,108,864 floats
constexpr size_t CACHE_BYTES = CACHE_ELEMS * sizeof(float);  // 256 MiB
constexpr int NEW_F4 = B * H * T * D4;                 // 65,536 float4 per tensor

// Scatter new k/v rows into the outputs at input_pos along S.
// k,v layout: (B, H, T, D). out layout: (B, H, S, D).
__global__ void kv_scatter_kernel(const int* __restrict__ input_pos,  // (B, T)
                                  const float4* __restrict__ k_new,
                                  const float4* __restrict__ v_new,
                                  float4* __restrict__ out_k,
                                  float4* __restrict__ out_v) {
    int i = blockIdx.x * blockDim.x + threadIdx.x;
    if (i >= NEW_F4) return;
    int d  = i % D4;
    int t  = (i / D4) % T;
    int h  = (i / (D4 * T)) % H;
    int b  = i / (D4 * T * H);
    int p  = input_pos[b * T + t];               // 0 <= p < S
    size_t dst = (((size_t)b * H + h) * S + p) * D4 + d;
    out_k[dst] = k_new[i];
    out_v[dst] = v_new[i];
}

extern "C" void kernel_launch(void* const* d_in, const int* in_sizes, int n_in,
                              void* d_out, int out_size, void* d_ws, size_t ws_size,
                              hipStream_t stream) {
    // setup_inputs order: input_pos, k, v, k_cache, v_cache
    const int*    input_pos = (const int*)d_in[0];
    const float4* k_new     = (const float4*)d_in[1];
    const float4* v_new     = (const float4*)d_in[2];
    const void*   k_cache   = (const void*)d_in[3];
    const void*   v_cache   = (const void*)d_in[4];

    float* out = (float*)d_out;
    float4* out_k = (float4*)out;
    float4* out_v = (float4*)(out + CACHE_ELEMS);

    // Bulk copies via the runtime's tuned D2D blit path (graph-capture legal).
    hipMemcpyAsync(out_k, k_cache, CACHE_BYTES, hipMemcpyDeviceToDevice, stream);
    hipMemcpyAsync(out_v, v_cache, CACHE_BYTES, hipMemcpyDeviceToDevice, stream);

    // Scatter: 65,536 float4 lanes -> 256 blocks x 256 threads (after copies
    // in stream order, so scattered rows overwrite copied rows).
    kv_scatter_kernel<<<(NEW_F4 + 255) / 256, 256, 0, stream>>>(
        input_pos, k_new, v_new, out_k, out_v);
}

// Round 3
// 206.825 us; speedup vs baseline: 1.0681x; 1.0049x over previous
//
#include <hip/hip_runtime.h>

// Problem constants (from reference): B=8, H=16, T=16, D=128, S=4096
constexpr int B = 8;
constexpr int H = 16;
constexpr int T = 16;
constexpr int D = 128;
constexpr int S = 4096;
constexpr int D4 = D / 4;                              // float4 per row = 32
constexpr size_t CACHE_ELEMS = (size_t)B * H * S * D;  // 67,108,864 floats
constexpr size_t CACHE_F4    = CACHE_ELEMS / 4;        // 16,777,216 float4
constexpr int NEW_F4 = B * H * T * D4;                 // 65,536 float4 per tensor

// Copy tuning: 2048 blocks x 256 threads; each half (k/v) gets 1024 blocks.
// Per thread: 64 float4 = 8 iters x 8-deep unrolled load batch.
constexpr int TPB = 256;
constexpr int COPY_BLOCKS = 2048;
constexpr int BLOCKS_PER_HALF = COPY_BLOCKS / 2;       // 1024
constexpr int UNROLL = 8;
constexpr int ITERS = 8;                                // 8*8 = 64 f4/thread
// sanity: 1024 * 256 * 64 = 16,777,216 = CACHE_F4

__global__ void __launch_bounds__(TPB)
kv_copy_kernel(const float4* __restrict__ k_cache,
               const float4* __restrict__ v_cache,
               float4* __restrict__ out) {
    int blk = blockIdx.x;
    const float4* __restrict__ src;
    float4* __restrict__ dst;
    if (blk < BLOCKS_PER_HALF) {
        src = k_cache;
        dst = out;
    } else {
        src = v_cache;
        dst = out + CACHE_F4;
        blk -= BLOCKS_PER_HALF;
    }
    size_t base = (size_t)blk * (TPB * UNROLL * ITERS) + threadIdx.x;
    for (int it = 0; it < ITERS; ++it) {
        size_t a = base + (size_t)it * (TPB * UNROLL);
        float4 r[UNROLL];
#pragma unroll
        for (int u = 0; u < UNROLL; ++u) r[u] = src[a + (size_t)u * TPB];
#pragma unroll
        for (int u = 0; u < UNROLL; ++u) dst[a + (size_t)u * TPB] = r[u];
    }
}

// Scatter new k/v rows into the outputs at input_pos along S.
// k,v layout: (B, H, T, D). out layout: (B, H, S, D).
__global__ void kv_scatter_kernel(const int* __restrict__ input_pos,  // (B, T)
                                  const float4* __restrict__ k_new,
                                  const float4* __restrict__ v_new,
                                  float4* __restrict__ out_k,
                                  float4* __restrict__ out_v) {
    int i = blockIdx.x * blockDim.x + threadIdx.x;
    if (i >= NEW_F4) return;
    int d  = i % D4;
    int t  = (i / D4) % T;
    int h  = (i / (D4 * T)) % H;
    int b  = i / (D4 * T * H);
    int p  = input_pos[b * T + t];               // 0 <= p < S
    size_t dst = (((size_t)b * H + h) * S + p) * D4 + d;
    out_k[dst] = k_new[i];
    out_v[dst] = v_new[i];
}

extern "C" void kernel_launch(void* const* d_in, const int* in_sizes, int n_in,
                              void* d_out, int out_size, void* d_ws, size_t ws_size,
                              hipStream_t stream) {
    // setup_inputs order: input_pos, k, v, k_cache, v_cache
    const int*    input_pos = (const int*)d_in[0];
    const float4* k_new     = (const float4*)d_in[1];
    const float4* v_new     = (const float4*)d_in[2];
    const float4* k_cache   = (const float4*)d_in[3];
    const float4* v_cache   = (const float4*)d_in[4];

    float* out = (float*)d_out;
    float4* out_k = (float4*)out;
    float4* out_v = (float4*)(out + CACHE_ELEMS);

    // One dispatch copies both caches into the contiguous output.
    kv_copy_kernel<<<COPY_BLOCKS, TPB, 0, stream>>>(k_cache, v_cache, out_k);

    // Scatter: 65,536 float4 lanes -> 256 blocks x 256 threads (after copy
    // in stream order, so scattered rows overwrite copied rows).
    kv_scatter_kernel<<<(NEW_F4 + 255) / 256, 256, 0, stream>>>(
        input_pos, k_new, v_new, out_k, out_v);
}

// Round 5
// 188.613 us; speedup vs baseline: 1.1712x; 1.0966x over previous
//
#include <hip/hip_runtime.h>

// Problem constants (from reference): B=8, H=16, T=16, D=128, S=4096
constexpr int B = 8;
constexpr int H = 16;
constexpr int T = 16;
constexpr int D = 128;
constexpr int S = 4096;
constexpr int D4 = D / 4;                              // float4 per row = 32
constexpr size_t CACHE_ELEMS = (size_t)B * H * S * D;  // 67,108,864 floats
constexpr size_t CACHE_F4    = CACHE_ELEMS / 4;        // 16,777,216 float4

// Native clang vector type — valid for __builtin_nontemporal_{load,store}.
typedef float f4 __attribute__((ext_vector_type(4)));

// Copy tuning: 2048 blocks x 256 threads; each half (k/v) gets 1024 blocks.
constexpr int TPB = 256;
constexpr int COPY_BLOCKS = 2048;
constexpr int BLOCKS_PER_HALF = COPY_BLOCKS / 2;       // 1024
constexpr int UNROLL = 8;
constexpr int ITERS = 8;                                // 8*8 = 64 f4/thread
constexpr int F4_PER_BLOCK = TPB * UNROLL * ITERS;      // 16384 f4 = 512 rows
constexpr int ROWS_PER_BLOCK = F4_PER_BLOCK / D4;       // 512 (within one b,h)
// sanity: 1024 * 16384 = 16,777,216 = CACHE_F4; S/ROWS_PER_BLOCK = 8 blocks/(b,h)

__global__ void __launch_bounds__(TPB)
kv_fused_kernel(const f4* __restrict__ k_cache,
                const f4* __restrict__ v_cache,
                const f4* __restrict__ k_new,
                const f4* __restrict__ v_new,
                const int* __restrict__ input_pos,      // (B, T)
                f4* __restrict__ out) {
    int blk = blockIdx.x;
    const f4* __restrict__ src;
    const f4* __restrict__ newsrc;
    f4* __restrict__ dst;
    if (blk < BLOCKS_PER_HALF) {
        src = k_cache; newsrc = k_new; dst = out;
    } else {
        blk -= BLOCKS_PER_HALF;
        src = v_cache; newsrc = v_new; dst = out + CACHE_F4;
    }

    // ---- Phase 1: bulk copy of this block's 512-row slice (non-temporal) ----
    size_t base = (size_t)blk * F4_PER_BLOCK + threadIdx.x;
    for (int it = 0; it < ITERS; ++it) {
        size_t a = base + (size_t)it * (TPB * UNROLL);
        f4 r[UNROLL];
#pragma unroll
        for (int u = 0; u < UNROLL; ++u)
            r[u] = __builtin_nontemporal_load(&src[a + (size_t)u * TPB]);
#pragma unroll
        for (int u = 0; u < UNROLL; ++u)
            __builtin_nontemporal_store(r[u], &dst[a + (size_t)u * TPB]);
    }

    // ---- Phase 2: overwrite scattered rows that land in this block's slice ----
    // Block covers (b,h) = blk/8, s in [s0, s0+512) with s0 = (blk%8)*512.
    __syncthreads();
    int bh = blk >> 3;                // b*H + h
    int b  = bh >> 4;                 // H = 16
    int s0 = (blk & 7) * ROWS_PER_BLOCK;
    int d4 = threadIdx.x & (D4 - 1);  // 0..31
    int tl = threadIdx.x >> 5;        // 0..7
#pragma unroll
    for (int tg = 0; tg < T / 8; ++tg) {
        int t = tg * 8 + tl;
        int p = input_pos[b * T + t];
        if (p >= s0 && p < s0 + ROWS_PER_BLOCK) {
            dst[((size_t)bh * S + p) * D4 + d4] =
                newsrc[((size_t)bh * T + t) * D4 + d4];
        }
    }
}

extern "C" void kernel_launch(void* const* d_in, const int* in_sizes, int n_in,
                              void* d_out, int out_size, void* d_ws, size_t ws_size,
                              hipStream_t stream) {
    // setup_inputs order: input_pos, k, v, k_cache, v_cache
    const int* input_pos = (const int*)d_in[0];
    const f4*  k_new     = (const f4*)d_in[1];
    const f4*  v_new     = (const f4*)d_in[2];
    const f4*  k_cache   = (const f4*)d_in[3];
    const f4*  v_cache   = (const f4*)d_in[4];

    f4* out = (f4*)d_out;

    // Single fused dispatch: copy both caches + in-block scatter overwrite.
    kv_fused_kernel<<<COPY_BLOCKS, TPB, 0, stream>>>(
        k_cache, v_cache, k_new, v_new, input_pos, out);
}